// Round 10
// baseline (381.182 us; speedup 1.0000x reference)
//
#include <hip/hip_runtime.h>

// Covariance: B=8, T=512, F=513, M=8, AVERAGE=True — fused coop kernel v2.
constexpr int kB  = 8;
constexpr int kT  = 512;
constexpr int kF  = 513;
constexpr int kM  = 8;
constexpr int kNP = 36;          // M*(M+1)/2 pairs
constexpr int kC  = 2 * kNP;     // 72 floats per (b,t,f)
constexpr int kFT = 64;          // f-tile width (= wave)
constexpr int kNFT = 9;          // ceil(F/64)
constexpr int kNTC = 8;          // t-chunks
constexpr int kTC  = kT / kNTC;  // 64 t per chunk
constexpr int kLDP = kC + 1;     // LDS row pad
constexpr int kS4  = kF * kC / 4;                    // f4 per (b,t) slice = 9234
constexpr unsigned kBreg4  = (unsigned)kT * kS4;     // f4 per b = 4,727,808
constexpr unsigned kTotal4 = (unsigned)kB * kBreg4;  // 37,822,464
constexpr unsigned kTF     = (unsigned)kT * kF;      // 262,656
constexpr int kGrid    = kB * kNFT * kNTC;           // 576 blocks
constexpr int kThreads = kGrid * 256;                // 147,456
constexpr int kSweeps  = (int)((kTotal4 + kThreads - 1) / kThreads);  // 257
constexpr size_t kWsNeed = 64 + (size_t)kB * kS4 * 16;  // barrier + means

// ---- grid barrier (generation-counting; bar zeroed each call) ----
__device__ __forceinline__ void gridbar(unsigned* bar, unsigned nb) {
  __syncthreads();
  if (threadIdx.x == 0) {
    __threadfence();
    unsigned g = __hip_atomic_load(&bar[1], __ATOMIC_RELAXED,
                                   __HIP_MEMORY_SCOPE_AGENT);
    unsigned old = __hip_atomic_fetch_add(&bar[0], 1u, __ATOMIC_ACQ_REL,
                                          __HIP_MEMORY_SCOPE_AGENT);
    if (old == nb - 1u) {
      __hip_atomic_store(&bar[0], 0u, __ATOMIC_RELAXED,
                         __HIP_MEMORY_SCOPE_AGENT);
      __hip_atomic_fetch_add(&bar[1], 1u, __ATOMIC_RELEASE,
                             __HIP_MEMORY_SCOPE_AGENT);
    } else {
      while (__hip_atomic_load(&bar[1], __ATOMIC_ACQUIRE,
                               __HIP_MEMORY_SCOPE_AGENT) == g)
        __builtin_amdgcn_s_sleep(2);
    }
  }
  __syncthreads();
}

// ---- shared phase-1 body (exact R1 partial; proven ~20us @576 blocks) ----
__device__ __forceinline__ void partial_body(const float* __restrict__ in,
                                             float* __restrict__ out,
                                             int bx, int tid, int wave, int lane,
                                             float (&buf)[2][kFT * kLDP]) {
  const int b  = bx / (kNFT * kNTC);
  const int r  = bx - b * (kNFT * kNTC);
  const int ft = r / kNTC;
  const int tc = r - ft * kNTC;
  const int f  = ft * kFT + lane;

  float accR[kNP], accI[kNP];
#pragma unroll
  for (int p = 0; p < kNP; ++p) { accR[p] = 0.0f; accI[p] = 0.0f; }

  if (f < kF) {
    const int t0 = tc * kTC + wave;
    const float* base = in + ((size_t)(b * kT + t0) * kF + f) * (2 * kM);
    const size_t tstep = (size_t)4 * kF * (2 * kM);
#pragma unroll 2
    for (int it = 0; it < kTC / 4; ++it) {
      const float* ptr = base + it * tstep;
      const float4 r0 = *(const float4*)(ptr + 0);
      const float4 r1 = *(const float4*)(ptr + 4);
      const float4 i0 = *(const float4*)(ptr + 8);
      const float4 i1 = *(const float4*)(ptr + 12);
      const float re[kM] = {r0.x, r0.y, r0.z, r0.w, r1.x, r1.y, r1.z, r1.w};
      const float im[kM] = {i0.x, i0.y, i0.z, i0.w, i1.x, i1.y, i1.z, i1.w};
      int p = 0;
#pragma unroll
      for (int i = 0; i < kM; ++i)
#pragma unroll
        for (int j = i; j < kM; ++j) {
          accR[p] += re[i] * re[j] + im[i] * im[j];
          accI[p] += re[i] * im[j] - im[i] * re[j];
          ++p;
        }
    }
  }

  float* my = buf[wave & 1] + lane * kLDP;
  if (wave < 2) {
#pragma unroll
    for (int p = 0; p < kNP; ++p) { my[p] = accR[p]; my[kNP + p] = accI[p]; }
  }
  __syncthreads();
  if (wave >= 2) {
#pragma unroll
    for (int p = 0; p < kNP; ++p) { my[p] += accR[p]; my[kNP + p] += accI[p]; }
  }
  __syncthreads();

  const int nf = min(kFT, kF - ft * kFT);
  float* dst = out + ((size_t)(b * kT + (1 + tc)) * kF + ft * kFT) * kC;
  const int n = nf * kC;
  for (int e = tid; e < n; e += 256) {
    const int l = (unsigned)e / (unsigned)kC;
    const int p = e - l * kC;
    dst[e] = buf[0][l * kLDP + p] + buf[1][l * kLDP + p];
  }
}

// ---- fused: partial -> bar -> combine(means->ws) -> bar -> stream-out ----
__global__ __launch_bounds__(256, 3)   // 3 blocks/CU guaranteed: 768 >= 576
void cov_fused(const float* __restrict__ in, float* __restrict__ out,
               unsigned* __restrict__ bar, float* __restrict__ ws) {
  const int tid  = threadIdx.x;
  const int wave = tid >> 6;
  const int lane = tid & 63;
  __shared__ float buf[2][kFT * kLDP];

  partial_body(in, out, blockIdx.x, tid, wave, lane, buf);

  gridbar(bar, (unsigned)gridDim.x);

  {  // combine: 8 partial slices -> mean, into ws (plain writes, no zeroing)
    const float4* __restrict__ o4 = (const float4*)out;
    float4* __restrict__ w4 = (float4*)ws;
    const unsigned idx0 = blockIdx.x * 256u + (unsigned)tid;
    if (idx0 < (unsigned)(kB * kS4)) {
      const unsigned b2 = idx0 / (unsigned)kS4;
      const unsigned fr = idx0 - b2 * (unsigned)kS4;
      const size_t base = (size_t)b2 * kBreg4;
      float4 s = make_float4(0.f, 0.f, 0.f, 0.f);
#pragma unroll
      for (int k = 0; k < kNTC; ++k) {
        const float4 v = o4[base + (size_t)(1 + k) * kS4 + fr];
        s.x += v.x; s.y += v.y; s.z += v.z; s.w += v.w;
      }
      const float sc = 1.0f / kT;
      s.x *= sc; s.y *= sc; s.z *= sc; s.w *= sc;
      w4[(size_t)b2 * kS4 + fr] = s;
    }
  }

  gridbar(bar, (unsigned)gridDim.x);

  {  // stream-out: linear write order; src (ws) and dst (out) provably
     // disjoint -> iterations pipeline (R8's alias serialization removed)
    const float4* __restrict__ w4 = (const float4*)ws;
    float4* __restrict__ o4 = (float4*)out;
    const unsigned idx0 = blockIdx.x * 256u + (unsigned)tid;
#pragma unroll 4
    for (int k = 0; k < kSweeps; ++k) {
      const unsigned idx = idx0 + (unsigned)k * (unsigned)kThreads;
      if (idx < kTotal4) {
        const unsigned g  = idx / 18u;          // record (b*T+t)*F + f
        const unsigned r  = idx - g * 18u;
        const unsigned b  = g / kTF;
        const unsigned f  = (g - b * kTF) % (unsigned)kF;
        o4[idx] = w4[(size_t)b * kS4 + f * 18u + r];
      }
    }
  }
}

// ---- fallback (proven 147us 3-kernel path) if ws too small ----
__global__ __launch_bounds__(256) void cov_partial(const float* __restrict__ in,
                                                   float* __restrict__ out) {
  __shared__ float buf[2][kFT * kLDP];
  partial_body(in, out, blockIdx.x, threadIdx.x, threadIdx.x >> 6,
               threadIdx.x & 63, buf);
}

__global__ __launch_bounds__(256) void cov_combine(float4* __restrict__ out) {
  const int total4 = kB * kS4;
  const int idx = blockIdx.x * 256 + threadIdx.x;
  if (idx >= total4) return;
  const int b = (unsigned)idx / (unsigned)kS4;
  const int fr4 = idx - b * kS4;
  const size_t bbase = (size_t)b * kBreg4;
  float4 s = make_float4(0.f, 0.f, 0.f, 0.f);
#pragma unroll
  for (int k = 0; k < kNTC; ++k) {
    const float4 v = out[bbase + (size_t)(1 + k) * kS4 + fr4];
    s.x += v.x; s.y += v.y; s.z += v.z; s.w += v.w;
  }
  const float sc = 1.0f / kT;
  s.x *= sc; s.y *= sc; s.z *= sc; s.w *= sc;
  out[bbase + fr4] = s;
}

__global__ __launch_bounds__(256) void cov_bcast(float4* __restrict__ out) {
  const unsigned idx = blockIdx.x * 256u + threadIdx.x;
  if (idx >= kTotal4) return;
  const unsigned g = idx / 18u;
  const unsigned r = idx - g * 18u;
  const unsigned b = g / kTF;
  const unsigned f = g % (unsigned)kF;
  out[idx] = out[(size_t)b * kBreg4 + f * 18u + r];
}

extern "C" void kernel_launch(void* const* d_in, const int* in_sizes, int n_in,
                              void* d_out, int out_size, void* d_ws, size_t ws_size,
                              hipStream_t stream) {
  const float* in = (const float*)d_in[0];
  float* out = (float*)d_out;

  if (ws_size >= kWsNeed) {
    unsigned* bar = (unsigned*)d_ws;
    float* means = (float*)((char*)d_ws + 64);
    hipMemsetAsync(d_ws, 0, 8, stream);   // barrier count+generation only
    cov_fused<<<dim3(kGrid), dim3(256), 0, stream>>>(in, out, bar, means);
  } else {
    cov_partial<<<dim3(kGrid), dim3(256), 0, stream>>>(in, out);
    const int total4 = kB * kS4;
    cov_combine<<<dim3((total4 + 255) / 256), dim3(256), 0, stream>>>((float4*)out);
    cov_bcast<<<dim3((kTotal4 + 255u) / 256u), dim3(256), 0, stream>>>((float4*)out);
  }
}